// Round 23
// baseline (51.144 us; speedup 1.0000x reference)
//
#include <hip/hip_runtime.h>
#include <hip/hip_bf16.h>
#include <stdint.h>

// Problem constants
#define B_ 16
#define C_ 256
#define H_ 64
#define W_ 64
#define WP 66                   // padded width: w' = w+1, border cols 0 and 65 zero
#define HP 66                   // padded height: h' = h+1, border rows 0 and 65 zero
#define ROWB (WP * 128)         // bytes per padded row of fp4 signs = 8448
#define STAGEB (3 * ROWB + 32)  // 3 rows staged + pad = 25376

typedef __attribute__((ext_vector_type(4))) float f32x4;
typedef __attribute__((ext_vector_type(16))) float f32x16;
typedef __attribute__((ext_vector_type(4))) int int4v;
typedef __attribute__((ext_vector_type(8))) int int8v;

typedef const __attribute__((address_space(1))) uint32_t* gptr_t;
typedef __attribute__((address_space(3))) uint32_t* lptr_t;

__device__ __forceinline__ void gl_lds16(const void* g, void* l) {
  __builtin_amdgcn_global_load_lds((gptr_t)g, (lptr_t)l, 16, 0, 0);
}

// fp4 e2m1 signs: +1 = 0x2, -1 = 0xA, 0 = 0x0 (exact)
__device__ __forceinline__ uint8_t sgn4(float v) {
  return v > 0.f ? (uint8_t)0x2 : (v < 0.f ? (uint8_t)0xA : (uint8_t)0);
}

// fp4 uses only the low 4 regs of the 8-reg f8f6f4 operand; upper 4 undef.
#define EXT8(v4) __builtin_shufflevector((v4), (v4), 0, 1, 2, 3, -1, -1, -1, -1)

// ---------- kernel A (MERGED): prep_w (blocks 0..255) + binarize (blocks 256..4351) ----------
// prep_w (32x32x64 layout): wtb[t][ot][kq][mi][lane][16B];
//   o = ot*64 + mi*32 + (l&31), c = kq*64 + (l>>5)*32 + j (nibble j of 16B).
// binarize (UNCHANGED from r22): a_p row b*66+(h+1), 66 pixel-blocks of 128B
//   = 8 chunks of 16B, chunk=(c>>5), stored chunk ^= (w'&7).
__global__ void prep_and_binarize(const float* __restrict__ w,
                                  float* __restrict__ scale,
                                  uint8_t* __restrict__ wtb,
                                  const float* __restrict__ x,
                                  const float* __restrict__ bias,
                                  uint8_t* __restrict__ a_p) {
  int tid = threadIdx.x;
  if (blockIdx.x < 256) {  // ---- prep_w ----
    int o = blockIdx.x, c = tid;
    const float* wo = w + (size_t)o * 2304 + (size_t)c * 9;  // w[o][c][kh][kw]
    float v[9];
    float s = 0.f;
#pragma unroll
    for (int t = 0; t < 9; ++t) { v[t] = wo[t]; s += fabsf(v[t]); }
    __shared__ float red[256];
    __shared__ uint8_t sg[9][256];
    red[c] = s;
#pragma unroll
    for (int t = 0; t < 9; ++t) sg[t][c] = sgn4(v[t]);
    __syncthreads();
    for (int st = 128; st > 0; st >>= 1) {
      if (c < st) red[c] += red[c + st];
      __syncthreads();
    }
    if (c == 0) scale[o] = red[0] / 2304.0f;
    if (c < 128) {  // thread c packs channels 2c, 2c+1 into one byte
      int k = c;
      int ot = o >> 6, mi = (o >> 5) & 1, lrow = o & 31;
      int kq = k >> 5, khalf = (k >> 4) & 1, jb = k & 15;
      int l = khalf * 32 + lrow;
#pragma unroll
      for (int t = 0; t < 9; ++t) {
        uint8_t byte = (uint8_t)(sg[t][2 * k] | (sg[t][2 * k + 1] << 4));
        wtb[(((((size_t)t * 4 + ot) * 4 + kq) * 2 + mi) * 64 + l) * 16 + jb] = byte;
      }
    }
    return;
  }
  // ---- binarize ----
  int id = blockIdx.x - 256;
  int bh = id >> 2, b = bh >> 6, h = bh & 63, c0 = (id & 3) * 64;
  __shared__ uint8_t lt[64][72];  // [w][ci], sgn4 value in low nibble
#pragma unroll
  for (int p = 0; p < 4; ++p) {
    int ci = p * 16 + (tid >> 4), w4 = (tid & 15) * 4;
    f32x4 v = *(const f32x4*)(x + (((size_t)(b * C_ + c0 + ci) * H_ + h) * W_ + w4));
    float bb = bias[c0 + ci];
#pragma unroll
    for (int k = 0; k < 4; ++k) lt[w4 + k][ci] = sgn4(v[k] + bb);
  }
  __syncthreads();
  size_t rowbase = (size_t)(b * HP + h + 1) * ROWB;
#pragma unroll
  for (int r = 0; r < 2; ++r) {
    int u = r * 256 + tid;             // 0..511 ; this y-block: 64 px x 8 u32
    int w_ = u >> 3, q = u & 7;        // q-th u32 (8 channels) of pixel w
    uint32_t val = 0;
#pragma unroll
    for (int e = 0; e < 8; ++e)
      val |= (uint32_t)(lt[w_][q * 8 + e] & 15) << (4 * e);
    int wp = w_ + 1;
    int ch = (c0 + q * 8) >> 5;
    int pos = wp * 128 + (((ch ^ wp) & 7) << 4) + (q & 3) * 4;
    *(uint32_t*)(a_p + rowbase + pos) = val;
  }
  // zero border pixel blocks; for edge h, zero the padded border rows.
  if ((id & 3) == 0) {
    if (tid < 32) *(uint32_t*)(a_p + rowbase + tid * 4) = 0;
    else if (tid < 64) *(uint32_t*)(a_p + rowbase + 65 * 128 + (tid - 32) * 4) = 0;
  }
  if (h == 0) {  // zero row h'=0 (quarter per y-block)
    uint32_t* zr = (uint32_t*)(a_p + (size_t)b * HP * ROWB) + (id & 3) * 528;
    for (int k = tid; k < 528; k += 256) zr[k] = 0;
  } else if (h == 63) {  // zero row h'=65
    uint32_t* zr = (uint32_t*)(a_p + ((size_t)b * HP + 65) * ROWB) + (id & 3) * 528;
    for (int k = tid; k < 528; k += 256) zr[k] = 0;
  }
}

// ---------- kernel B: binary conv, MX-fp4 32x32x64 MFMA (2x FLOPs/instr) ----------
// Round-23: mfma_scale_f32_32x32x64_f8f6f4 halves the instruction stream
// (144 vs 288 MFMAs/wave; loads halved too) — targeting the issue-bound
// plateau (MfmaUtil ~30% across all r9-r20 scheduling variants).
// Wave tile: 64 ch x 64 px as 2x2 of 32x32; acc = 4x f32x16 = 64 AGPRs.
// Schedule mirrors r19: W ping-pong one half-tap ahead, B JIT from LDS.
// A-frag: lane l row=l&31, k=(l>>5)*32+j. C/D: col=l&31,
// row=(r&3)+8*(r>>2)+4*(l>>5) (guide-verified 32x32 map).
#define LOADW(dst, t, kh) {                                                       \
  _Pragma("unroll") for (int q = 0; q < 2; ++q)                                   \
  _Pragma("unroll") for (int mi = 0; mi < 2; ++mi)                                \
      dst[q * 2 + mi] = *(const int4v*)(wtb +                                     \
        (((((size_t)(t) * 4 + wv) * 4 + (kh) * 2 + q) * 2 + mi) * 64 + l) * 16); }

#define LOADB(dst, d, dxi, kh) {                                                  \
  _Pragma("unroll") for (int q = 0; q < 2; ++q)                                   \
  _Pragma("unroll") for (int ni = 0; ni < 2; ++ni) {                              \
    int wp_ = ni * 32 + (l & 31) + (dxi);                                         \
    int ch_ = ((kh) * 2 + q) * 2 + (l >> 5);                                      \
    dst[q * 2 + ni] = *(const int4v*)(smem + (d) * ROWB + wp_ * 128 +             \
                                      (((ch_ ^ wp_) & 7) << 4)); } }

#define MFMA_BURST(wreg, breg)                                                    \
  __builtin_amdgcn_s_setprio(1);                                                  \
  _Pragma("unroll") for (int q = 0; q < 2; ++q)  /* q outermost: dependent */     \
  _Pragma("unroll") for (int mi = 0; mi < 2; ++mi) /* acc reuse 4 MFMAs apart */  \
  _Pragma("unroll") for (int ni = 0; ni < 2; ++ni)                                \
      acc[mi][ni] = __builtin_amdgcn_mfma_scale_f32_32x32x64_f8f6f4(              \
          EXT8(wreg[q * 2 + mi]), EXT8(breg[q * 2 + ni]), acc[mi][ni],            \
          4, 4, 0, 127, 0, 127);                                                  \
  __builtin_amdgcn_s_setprio(0);

__global__ __launch_bounds__(256, 3) void bconv(
    const uint8_t* __restrict__ a_p, const uint8_t* __restrict__ wtb,
    const float* __restrict__ scale, const float* __restrict__ x,
    const float* __restrict__ pb0, const float* __restrict__ alpha,
    const float* __restrict__ pb1, float* __restrict__ out) {
  __shared__ __attribute__((aligned(16))) uint8_t smem[STAGEB];
  // XCD-aware bijective swizzle: 1024 blocks, 8 XCDs, 128 contiguous per XCD
  int bh = (blockIdx.x & 7) * 128 + (blockIdx.x >> 3);
  int b = bh >> 6, h = bh & 63;
  int tid = threadIdx.x, l = tid & 63, wv = tid >> 6;
  int wm = wv * 64;

  // stage 3 contiguous padded rows (h', h'+1, h'+2) = input rows h-1,h,h+1
  const uint8_t* src = a_p + (size_t)(b * HP + h) * ROWB;
#pragma unroll
  for (int it = 0; it < 6; ++it)
    gl_lds16(src + (size_t)(it * 256 + tid) * 16, smem + it * 4096 + wv * 1024);
  if (tid < 48) gl_lds16(src + 24576 + (size_t)tid * 16, smem + 24576);

  f32x16 acc[2][2];
#pragma unroll
  for (int i = 0; i < 2; ++i)
#pragma unroll
    for (int j = 0; j < 2; ++j) acc[i][j] = (f32x16)(0.f);

  asm volatile("s_waitcnt vmcnt(0)" ::: "memory");
  __syncthreads();

  int4v wA[4], wB[4], bf[4];
  LOADW(wA, 0, 0)
#pragma unroll 1
  for (int t = 0; t < 9; ++t) {      // tap loop NOT unrolled: fences code motion
    int d = t / 3, dxi = t - d * 3;
    // half-tap kh=0: prefetch (t,1) into wB, B JIT, burst with wA
    LOADW(wB, t, 1)
    LOADB(bf, d, dxi, 0)
    MFMA_BURST(wA, bf)
    // half-tap kh=1: prefetch (t+1,0) into wA, B JIT, burst with wB
    if (t < 8) { LOADW(wA, t + 1, 0) }
    LOADB(bf, d, dxi, 1)
    MFMA_BURST(wB, bf)
  }

  // epilogue: conv*scale + pb0 -> PReLU -> + pb1 + x (residual)
  size_t xb = (size_t)b * C_ * H_ * W_ + (size_t)h * W_;
  int lhi = l >> 5;                   // C/D row offset 4*(lane>>5)
#pragma unroll
  for (int mi = 0; mi < 2; ++mi) {
#pragma unroll
    for (int r = 0; r < 16; ++r) {
      int o = wm + mi * 32 + (r & 3) + 8 * (r >> 2) + 4 * lhi;
      float sc = scale[o], b0 = pb0[o], al = alpha[o], b1 = pb1[o];
      size_t rowo = xb + (size_t)o * (H_ * W_);
#pragma unroll
      for (int ni = 0; ni < 2; ++ni) {
        int wcol = ni * 32 + (l & 31);  // C/D col = lane&31
        float v = acc[mi][ni][r] * sc + b0;
        v = v >= 0.f ? v : al * v;
        v = v + b1 + x[rowo + wcol];
        out[rowo + wcol] = v;
      }
    }
  }
}

extern "C" void kernel_launch(void* const* d_in, const int* in_sizes, int n_in,
                              void* d_out, int out_size, void* d_ws, size_t ws_size,
                              hipStream_t stream) {
  const float* x     = (const float*)d_in[0];
  const float* m0b   = (const float*)d_in[1];
  const float* w     = (const float*)d_in[2];
  const float* pb0   = (const float*)d_in[3];
  const float* alpha = (const float*)d_in[4];
  const float* pb1   = (const float*)d_in[5];
  float* out = (float*)d_out;

  // ws: [0,4KB) scale | [4096, +294912+pad) wtb fp4 | a_p padded 16*66*8448 = 8.9MB
  float* scale = (float*)d_ws;
  uint8_t* wtb = (uint8_t*)d_ws + 4096;
  uint8_t* a_p = (uint8_t*)d_ws + 4096 + (size_t)9 * 4 * 4 * 2 * 1024 + 1024;

  hipLaunchKernelGGL(prep_and_binarize, dim3(256 + B_ * H_ * 4), dim3(256), 0,
                     stream, w, scale, wtb, x, m0b, a_p);
  hipLaunchKernelGGL(bconv, dim3(B_ * H_), dim3(256), 0, stream,
                     a_p, wtb, scale, x, pb0, alpha, pb1, out);
}